// Round 8
// baseline (1038.290 us; speedup 1.0000x reference)
//
#include <hip/hip_runtime.h>
#include <hip/hip_bf16.h>

// Problem dims (fixed by reference): x[B*S=8192, E=2048], w1/w2[H=8192, E], w3[E, H]
#define M_ROWS 8192
#define E_DIM  2048
#define H_DIM  8192

typedef __attribute__((ext_vector_type(8))) short bf16x8;
typedef __attribute__((ext_vector_type(16))) float f32x16;
typedef __attribute__((ext_vector_type(4))) unsigned int uint4v;

__device__ __forceinline__ unsigned short f2bf_rne(float x) {
  unsigned u = __builtin_bit_cast(unsigned, x);
  u += 0x7FFFu + ((u >> 16) & 1u);
  return (unsigned short)(u >> 16);
}

__device__ __forceinline__ float bf2f(unsigned short b) {
  unsigned u = ((unsigned)b) << 16;
  return __builtin_bit_cast(float, u);
}

// ---------------- fp32 -> bf16 conversion (memory-bound, vectorized) ----------------
__global__ __launch_bounds__(256) void cvt_f32_bf16(const float* __restrict__ in,
                                                    unsigned short* __restrict__ out,
                                                    int n8) {
  int i = blockIdx.x * blockDim.x + threadIdx.x;
  if (i >= n8) return;
  const float4* p = (const float4*)(in + (size_t)i * 8);
  float4 a = p[0];
  float4 b = p[1];
  union { unsigned short us[8]; uint4v v; } r;
  r.us[0] = f2bf_rne(a.x); r.us[1] = f2bf_rne(a.y);
  r.us[2] = f2bf_rne(a.z); r.us[3] = f2bf_rne(a.w);
  r.us[4] = f2bf_rne(b.x); r.us[5] = f2bf_rne(b.y);
  r.us[6] = f2bf_rne(b.z); r.us[7] = f2bf_rne(b.w);
  *(uint4v*)(out + (size_t)i * 8) = r.v;
}

// ---------------- async global -> LDS, 16B per lane ----------------
__device__ __forceinline__ void gld_lds16(const unsigned short* g, unsigned short* l) {
  __builtin_amdgcn_global_load_lds(
      (const __attribute__((address_space(1))) unsigned int*)g,
      (__attribute__((address_space(3))) unsigned int*)l, 16, 0, 0);
}

#define VMCNT(n)   asm volatile("s_waitcnt vmcnt(" #n ")" ::: "memory")

// ====== 256x256 8-phase/2-K-tile GEMM (m201 cadence, 32x32x16 MFMA, fragment-linear LDS) ======
// C[M,N] = A[M,K]*B[N,K]^T. 512 threads (8 waves 2Mx4N), BK=64, buf0=even buf1=odd K-tiles.
// LDS layout = MFMA fragment order: tile (256x64) = 32 blocks of 1KiB; block (msub,ks)
// holds the 32x16 fragment lane-ordered: elem = block*512 + lane*8 + e, where
// row = msub*32 + (lane&31), k = ks*16 + (lane>>5)*8. Reads are ds_read_b128 at
// base + lane*16 + imm -> conflict-free by construction, no swizzle, no addr math.
// Each wave's global_load_lds 1KiB chunk = exactly one fragment block (source offsets
// precomputed per thread). Phase skeleton IDENTICAL to R7 (verified): per phase
// { ds_reads | stage | [lgkm(8) if 12 rds] | bar | lgkmcnt(0) | sched_barrier |
//   setprio(1) | 8 MFMA (one quadrant) | setprio(0) | [vmcnt(6) at ph4/ph8] | bar }.
// Reads/phase: 12/4/8/0. Quadrants: (ms0-1,ns0),(ms0-1,ns1),(ms2-3,ns0),(ms2-3,ns1).
// Stage cadence (deadline order; t even): ph1: A.H1(t+1)  ph3: B.H0(t+2)
//   ph4: B.H1(t+2),A.H0(t+2)  ph5: A.H1(t+2)  ph7: B.H0(t+3)  ph8: B.H1(t+3),A.H0(t+3)
// WAR ledger + vmcnt(6) induction unchanged from R7 (stage instr counts identical).
// EPI=0: fp32 store; EPI=1: bf16 store; EPI=2: bf16 silu(Gate[idx]) * acc store.
template <int EPI>
__global__ __launch_bounds__(512, 2)
void gemm256(const unsigned short* __restrict__ A,
             const unsigned short* __restrict__ B,
             const unsigned short* __restrict__ Gate,
             void* __restrict__ Cout,
             int M, int N, int K) {
  __shared__ unsigned short lA[2][16384];  // [parity][block*512 + lane*8 + e]
  __shared__ unsigned short lB[2][16384];

  const int tid = threadIdx.x;
  const int lane = tid & 63;
  const int wave = tid >> 6;
  const int wr = wave >> 2;   // 0..1  (128 output rows each)
  const int wc = wave & 3;    // 0..3  (64 output cols each)
  const int wr4 = wr * 4, wc2 = wc * 2;

  // bijective XCD swizzle (nwg % 8 == 0 for all launches here)
  const int gx = gridDim.x;
  const int nwg = gx * gridDim.y;
  const int wg = blockIdx.y * gx + blockIdx.x;
  const int swz = (wg & 7) * (nwg >> 3) + (wg >> 3);
  const int bcol = swz % gx, brow = swz / gx;

  const unsigned short* Ag = A + (size_t)brow * 256 * K;
  const unsigned short* Bg = B + (size_t)bcol * 256 * K;

  f32x16 acc[4][2] = {};
  const int NT = K >> 6;
  const int NI = NT >> 1;

  // Per-thread stage source offsets (fragment-linear decode), fixed for all halves:
  // i-th gld: dest elem ep[i] = i*4096 + tid*8; block = ep>>9; l = (ep>>3)&63;
  // row = (block>>2)*32 + (l&31); k = (block&3)*16 + (l>>5)*8; soff = row*K + k.
  const int ep0 = tid * 8, ep1 = 4096 + tid * 8;
  size_t soff0, soff1;
  {
    int blk = ep0 >> 9, l = (ep0 >> 3) & 63;
    soff0 = (size_t)((blk >> 2) * 32 + (l & 31)) * K + ((blk & 3) * 16 + ((l >> 5) << 3));
    blk = ep1 >> 9; l = (ep1 >> 3) & 63;
    soff1 = (size_t)((blk >> 2) * 32 + (l & 31)) * K + ((blk & 3) * 16 + ((l >> 5) << 3));
  }
  // stage one 128-row half-tile (16 fragment blocks, 16KiB)
  auto stageH = [&](const unsigned short* gbase, unsigned short* ldsh) {
    gld_lds16(gbase + soff0, ldsh + ep0);
    gld_lds16(gbase + soff1, ldsh + ep1);
  };

  bf16x8 afr[4][4], bfr[2][4];

#define RD_A(MLO, SRC) \
  _Pragma("unroll") for (int ms = MLO; ms < MLO + 2; ++ms) \
  _Pragma("unroll") for (int ks = 0; ks < 4; ++ks) \
    afr[ms][ks] = *(const bf16x8*)&SRC[(((wr4 + ms) << 2) + ks) * 512 + (lane << 3)];
#define RD_B(NS, SRC) \
  _Pragma("unroll") for (int ks = 0; ks < 4; ++ks) \
    bfr[NS][ks] = *(const bf16x8*)&SRC[(((wc2 + NS) << 2) + ks) * 512 + (lane << 3)];
#define PH_MFMA(MLO, NS) \
  __builtin_amdgcn_s_barrier(); \
  asm volatile("s_waitcnt lgkmcnt(0)" ::: "memory"); \
  __builtin_amdgcn_sched_barrier(0); \
  __builtin_amdgcn_s_setprio(1); \
  _Pragma("unroll") for (int ms = MLO; ms < MLO + 2; ++ms) \
  _Pragma("unroll") for (int ks = 0; ks < 4; ++ks) \
    acc[ms][NS] = __builtin_amdgcn_mfma_f32_32x32x16_bf16(afr[ms][ks], bfr[NS][ks], acc[ms][NS], 0, 0, 0); \
  __builtin_amdgcn_s_setprio(0);

  // ---------------- prologue: stage tiles 0 and 1 fully; drain; barrier ----------------
  stageH(Ag, &lA[0][0]);
  stageH(Ag + (size_t)128 * K, &lA[0][8192]);
  stageH(Bg, &lB[0][0]);
  stageH(Bg + (size_t)128 * K, &lB[0][8192]);
  stageH(Ag + 64, &lA[1][0]);
  stageH(Ag + (size_t)128 * K + 64, &lA[1][8192]);
  stageH(Bg + 64, &lB[1][0]);
  stageH(Bg + (size_t)128 * K + 64, &lB[1][8192]);
  VMCNT(0);
  __builtin_amdgcn_s_barrier();

  const unsigned short* lA0 = &lA[0][0];
  const unsigned short* lB0 = &lB[0][0];
  const unsigned short* lA1 = &lA[1][0];
  const unsigned short* lB1 = &lB[1][0];

  for (int it = 0; it < NI; ++it) {
    const int t = it << 1;
    const size_t kT1 = (size_t)(t + 1) * 64;
    const size_t kS2 = (size_t)((t + 2 < NT) ? t + 2 : NT - 1) * 64;
    const size_t kS3 = (size_t)((t + 3 < NT) ? t + 3 : NT - 1) * 64;

    // ---- ph1: rd A ms0-1 + B ns0 (12) | stage A.H1(t+1) | lgkm(8) | Q(0,0)
    RD_A(0, lA0); RD_B(0, lB0);
    if (it > 0) stageH(Ag + (size_t)128 * K + kT1, &lA[1][8192]);
    asm volatile("s_waitcnt lgkmcnt(8)" ::: "memory");
    PH_MFMA(0, 0);
    __builtin_amdgcn_s_barrier();

    // ---- ph2: rd B ns1 (4) | Q(0,1)
    RD_B(1, lB0);
    PH_MFMA(0, 1);
    __builtin_amdgcn_s_barrier();

    // ---- ph3: rd A ms2-3 (8) | stage B.H0(t+2) | Q(2,0)
    RD_A(2, lA0);
    stageH(Bg + kS2, &lB[0][0]);
    PH_MFMA(2, 0);
    __builtin_amdgcn_s_barrier();

    // ---- ph4: stage B.H1(t+2), A.H0(t+2) | Q(2,1) | vmcnt(6)
    stageH(Bg + (size_t)128 * K + kS2, &lB[0][8192]);
    stageH(Ag + kS2, &lA[0][0]);
    PH_MFMA(2, 1);
    VMCNT(6);
    __builtin_amdgcn_s_barrier();

    // ---- ph5: rd A ms0-1 + B ns0 of t+1 | stage A.H1(t+2) | lgkm(8) | Q(0,0)
    RD_A(0, lA1); RD_B(0, lB1);
    stageH(Ag + (size_t)128 * K + kS2, &lA[0][8192]);
    asm volatile("s_waitcnt lgkmcnt(8)" ::: "memory");
    PH_MFMA(0, 0);
    __builtin_amdgcn_s_barrier();

    // ---- ph6: rd B ns1 of t+1 | Q(0,1)
    RD_B(1, lB1);
    PH_MFMA(0, 1);
    __builtin_amdgcn_s_barrier();

    // ---- ph7: rd A ms2-3 of t+1 | stage B.H0(t+3) | Q(2,0)
    RD_A(2, lA1);
    stageH(Bg + kS3, &lB[1][0]);
    PH_MFMA(2, 0);
    __builtin_amdgcn_s_barrier();

    // ---- ph8: stage B.H1(t+3), A.H0(t+3) | Q(2,1) | vmcnt(6)
    stageH(Bg + (size_t)128 * K + kS3, &lB[1][8192]);
    stageH(Ag + kS3, &lA[1][0]);
    PH_MFMA(2, 1);
    VMCNT(6);
    __builtin_amdgcn_s_barrier();
  }
  VMCNT(0);  // drain tail stages before any wave exits (LDS dealloc safety)

#undef RD_A
#undef RD_B
#undef PH_MFMA

  // Epilogue. 32x32 C/D layout (measured, m74/m101): col = lane&31,
  // row = (reg&3) + 8*(reg>>2) + 4*(lane>>5).
  const int row0 = brow * 256 + wr * 128 + 4 * (lane >> 5);
  const int col0 = bcol * 256 + wc * 64 + (lane & 31);
#pragma unroll
  for (int ms = 0; ms < 4; ++ms) {
#pragma unroll
    for (int ns = 0; ns < 2; ++ns) {
#pragma unroll
      for (int reg = 0; reg < 16; ++reg) {
        int r = row0 + ms * 32 + (reg & 3) + 8 * (reg >> 2);
        size_t idx = (size_t)r * N + (col0 + ns * 32);
        float v = acc[ms][ns][reg];
        if constexpr (EPI == 0) {
          ((float*)Cout)[idx] = v;
        } else if constexpr (EPI == 1) {
          ((unsigned short*)Cout)[idx] = f2bf_rne(v);
        } else {
          float g = bf2f(Gate[idx]);
          float s = g / (1.0f + __expf(-g));  // silu
          ((unsigned short*)Cout)[idx] = f2bf_rne(s * v);
        }
      }
    }
  }
}

extern "C" void kernel_launch(void* const* d_in, const int* in_sizes, int n_in,
                              void* d_out, int out_size, void* d_ws, size_t ws_size,
                              hipStream_t stream) {
  const float* x  = (const float*)d_in[0];
  const float* w1 = (const float*)d_in[1];
  const float* w2 = (const float*)d_in[2];
  const float* w3 = (const float*)d_in[3];
  float* out = (float*)d_out;

  const int M = M_ROWS, E = E_DIM, H = H_DIM;

  // ws layout (bf16 elements):
  //   [0, 32MB)   xb   (reused for w3b after up-GEMM)
  //   [32, 64MB)  w1b  (reused for w2b after gate-GEMM)
  //   [64, 192MB) gate -> h (silu-mul written in-place)
  unsigned short* xb  = (unsigned short*)d_ws;
  unsigned short* w1b = xb + (size_t)M * E;
  unsigned short* gb  = w1b + (size_t)H * E;
  unsigned short* w2b = w1b;  // safe: cvt(w2) is stream-ordered after gate-GEMM reads w1b
  unsigned short* w3b = xb;   // safe: cvt(w3) is stream-ordered after up-GEMM reads xb

  const int n8 = (M * E) / 8;  // == (H*E)/8 == (E*H)/8 == 2097152
  cvt_f32_bf16<<<dim3(n8 / 256), 256, 0, stream>>>(x, xb, n8);
  cvt_f32_bf16<<<dim3(n8 / 256), 256, 0, stream>>>(w1, w1b, n8);

  // gate = x w1^T  -> bf16 [M, H]
  gemm256<1><<<dim3(H / 256, M / 256), 512, 0, stream>>>(xb, w1b, nullptr, gb, M, H, E);

  cvt_f32_bf16<<<dim3(n8 / 256), 256, 0, stream>>>(w2, w2b, n8);

  // h = silu(gate) * (x w2^T) -> bf16 [M, H], in-place over gate
  gemm256<2><<<dim3(H / 256, M / 256), 512, 0, stream>>>(xb, w2b, gb, gb, M, H, E);

  cvt_f32_bf16<<<dim3(n8 / 256), 256, 0, stream>>>(w3, w3b, n8);

  // out = h w3^T -> fp32 [M, E]
  gemm256<0><<<dim3(E / 256, M / 256), 512, 0, stream>>>(gb, w3b, nullptr, out, M, E, H);
}

// Round 10
// 832.469 us; speedup vs baseline: 1.2472x; 1.2472x over previous
//
#include <hip/hip_runtime.h>
#include <hip/hip_bf16.h>

// Problem dims (fixed by reference): x[B*S=8192, E=2048], w1/w2[H=8192, E], w3[E, H]
#define M_ROWS 8192
#define E_DIM  2048
#define H_DIM  8192

typedef __attribute__((ext_vector_type(8))) short bf16x8;
typedef __attribute__((ext_vector_type(4))) float f32x4;
typedef __attribute__((ext_vector_type(4))) unsigned int uint4v;

__device__ __forceinline__ unsigned short f2bf_rne(float x) {
  unsigned u = __builtin_bit_cast(unsigned, x);
  u += 0x7FFFu + ((u >> 16) & 1u);
  return (unsigned short)(u >> 16);
}

// ---------------- fp32 -> bf16 conversion, 3 segments per launch ----------------
__global__ __launch_bounds__(256) void cvt3_f32_bf16(const float* __restrict__ s0, unsigned short* __restrict__ d0,
                                                     const float* __restrict__ s1, unsigned short* __restrict__ d1,
                                                     const float* __restrict__ s2, unsigned short* __restrict__ d2,
                                                     int n8) {
  int i = blockIdx.x * blockDim.x + threadIdx.x;
  if (i >= n8) return;
  const float* in = (blockIdx.y == 0) ? s0 : (blockIdx.y == 1) ? s1 : s2;
  unsigned short* out = (blockIdx.y == 0) ? d0 : (blockIdx.y == 1) ? d1 : d2;
  const float4* p = (const float4*)(in + (size_t)i * 8);
  float4 a = p[0];
  float4 b = p[1];
  union { unsigned short us[8]; uint4v v; } r;
  r.us[0] = f2bf_rne(a.x); r.us[1] = f2bf_rne(a.y);
  r.us[2] = f2bf_rne(a.z); r.us[3] = f2bf_rne(a.w);
  r.us[4] = f2bf_rne(b.x); r.us[5] = f2bf_rne(b.y);
  r.us[6] = f2bf_rne(b.z); r.us[7] = f2bf_rne(b.w);
  *(uint4v*)(out + (size_t)i * 8) = r.v;
}

// ---------------- async global -> LDS, 16B per lane ----------------
__device__ __forceinline__ void gld_lds16(const unsigned short* g, unsigned short* l) {
  __builtin_amdgcn_global_load_lds(
      (const __attribute__((address_space(1))) unsigned int*)g,
      (__attribute__((address_space(3))) unsigned int*)l, 16, 0, 0);
}

#define VMCNT(n)   asm volatile("s_waitcnt vmcnt(" #n ")" ::: "memory")

// =============== 256-row 8-phase/2-K-tile GEMM (m201 cadence, R7-verified) ===============
// 512 threads (8 waves 2Mx4N), BK=64, buf0=even buf1=odd K-tiles, 128KiB LDS (single
// flat array: lA = sh, lB = sh+32768), XOR-swizzled LDS reads via pre-swizzled global
// source (linear LDS dest), bijective XCD swizzle, setprio on MFMA, vmcnt(6) at
// ph4/ph8 (loads aged 3-5 phases), lgkm(8) hint on 12-read phases. Phase skeleton
// IDENTICAL to R7 (verified 340us/GEMM).
// EPI=0: single-B 256x256 tile, fp32 store (down-proj).
// EPI=3: FUSED gate+up. Tile = 256 rows x 128 cols of BOTH matmuls. B-LDS rows
//   0-127 <- w1 panel (B), rows 128-255 <- w2 panel (B2). Waves wc in {0,1} compute
//   gate, wc in {2,3} compute up of the SAME output cols. Epilogue: up-waves dump
//   acc f32 to LDS (conflict-free lane-contiguous), barrier, gate-waves combine
//   silu(g)*u -> bf16 store. Gate never touches global memory; x staged once.
template <int EPI>
__global__ __launch_bounds__(512, 2)
void gemm256(const unsigned short* __restrict__ A,
             const unsigned short* __restrict__ B,
             const unsigned short* __restrict__ B2,
             void* __restrict__ Cout,
             int M, int N, int K) {
  __shared__ unsigned short sh[65536];     // 128KiB: [0,32768)=lA dbuf, [32768,65536)=lB dbuf
  unsigned short* lAb = sh;                // lA[parity] = lAb + parity*16384
  unsigned short* lBb = sh + 32768;        // lB[parity] = lBb + parity*16384

  const int tid = threadIdx.x;
  const int lane = tid & 63;
  const int wave = tid >> 6;
  const int wr = wave >> 2;   // 0..1  (128 output rows each)
  const int wc = wave & 3;    // 0..3
  const int lr = lane & 15, lk = lane >> 4;

  // bijective XCD swizzle (nwg % 8 == 0 for all launches here)
  const int gx = gridDim.x;
  const int nwg = gx * gridDim.y;
  const int wg = blockIdx.y * gx + blockIdx.x;
  const int swz = (wg & 7) * (nwg >> 3) + (wg >> 3);
  const int bcol = swz % gx, brow = swz / gx;

  const unsigned short* Ag = A + (size_t)brow * 256 * K;
  const unsigned short* BgH0;  // source for B-LDS rows 0-127
  const unsigned short* BgH1;  // source for B-LDS rows 128-255
  if constexpr (EPI == 3) {
    BgH0 = B  + (size_t)bcol * 128 * K;   // w1 panel
    BgH1 = B2 + (size_t)bcol * 128 * K;   // w2 panel
  } else {
    BgH0 = B + (size_t)bcol * 256 * K;
    BgH1 = BgH0 + (size_t)128 * K;
  }

  f32x4 acc[8][4] = {};
  const int NT = K >> 6;
  const int NI = NT >> 1;

  // stage one 128x64 half-tile: linear LDS dest (lane*16B), inverse-swizzled global src
  auto stageH = [&](const unsigned short* gbase, unsigned short* ldsh) {
#pragma unroll
    for (int i = 0; i < 2; ++i) {
      int p = i * 4096 + tid * 8;               // physical element offset in half
      int row = p >> 6;                          // 0..127
      int lslot = ((p >> 3) & 7) ^ (row & 7);    // logical 8-elem slot
      gld_lds16(gbase + (size_t)row * K + lslot * 8, ldsh + p);
    }
  };

  const int xsw = (lr & 7) << 3;  // read-side swizzle XOR (element units)
  bf16x8 af[8][2], bf[4][2];

#define RD_A(MLO, SRC) \
  _Pragma("unroll") for (int m = MLO; m < MLO + 4; ++m) { \
    int r = wr * 128 + m * 16 + lr; \
    af[m][0] = *(const bf16x8*)&SRC[(r * 64 + lk * 8) ^ xsw]; \
    af[m][1] = *(const bf16x8*)&SRC[(r * 64 + 32 + lk * 8) ^ xsw]; }
#define RD_B(NLO, SRC) \
  _Pragma("unroll") for (int n = NLO; n < NLO + 2; ++n) { \
    int r = wc * 64 + n * 16 + lr; \
    bf[n][0] = *(const bf16x8*)&SRC[(r * 64 + lk * 8) ^ xsw]; \
    bf[n][1] = *(const bf16x8*)&SRC[(r * 64 + 32 + lk * 8) ^ xsw]; }
#define PH_MFMA(MLO, NLO) \
  __builtin_amdgcn_s_barrier(); \
  asm volatile("s_waitcnt lgkmcnt(0)" ::: "memory"); \
  __builtin_amdgcn_sched_barrier(0); \
  __builtin_amdgcn_s_setprio(1); \
  _Pragma("unroll") for (int m = MLO; m < MLO + 4; ++m) \
  _Pragma("unroll") for (int n = NLO; n < NLO + 2; ++n) \
  _Pragma("unroll") for (int ks = 0; ks < 2; ++ks) \
    acc[m][n] = __builtin_amdgcn_mfma_f32_16x16x32_bf16(af[m][ks], bf[n][ks], acc[m][n], 0, 0, 0); \
  __builtin_amdgcn_s_setprio(0);

  // ---------------- prologue: stage tiles 0 and 1 fully; drain; barrier ----------------
  stageH(Ag, lAb);
  stageH(Ag + (size_t)128 * K, lAb + 8192);
  stageH(BgH0, lBb);
  stageH(BgH1, lBb + 8192);
  stageH(Ag + 64, lAb + 16384);
  stageH(Ag + (size_t)128 * K + 64, lAb + 16384 + 8192);
  stageH(BgH0 + 64, lBb + 16384);
  stageH(BgH1 + 64, lBb + 16384 + 8192);
  VMCNT(0);
  __builtin_amdgcn_s_barrier();

  const unsigned short* lA0 = lAb;
  const unsigned short* lB0 = lBb;
  const unsigned short* lA1 = lAb + 16384;
  const unsigned short* lB1 = lBb + 16384;

  for (int it = 0; it < NI; ++it) {
    const int t = it << 1;
    const size_t kT1 = (size_t)(t + 1) * 64;
    const size_t kS2 = (size_t)((t + 2 < NT) ? t + 2 : NT - 1) * 64;
    const size_t kS3 = (size_t)((t + 3 < NT) ? t + 3 : NT - 1) * 64;

    // ---- ph1: rd af[0-3]+bf[0-1] (12) | stage A.H1(t+1) | lgkm(8) | Q(0,0)
    RD_A(0, lA0); RD_B(0, lB0);
    if (it > 0) stageH(Ag + (size_t)128 * K + kT1, lAb + 16384 + 8192);
    asm volatile("s_waitcnt lgkmcnt(8)" ::: "memory");
    PH_MFMA(0, 0);
    __builtin_amdgcn_s_barrier();

    // ---- ph2: rd bf[2-3] (4) | Q(0,2)
    RD_B(2, lB0);
    PH_MFMA(0, 2);
    __builtin_amdgcn_s_barrier();

    // ---- ph3: rd af[4-7] (8) | stage B.H0(t+2) | Q(4,0)
    RD_A(4, lA0);
    stageH(BgH0 + kS2, lBb);
    PH_MFMA(4, 0);
    __builtin_amdgcn_s_barrier();

    // ---- ph4: stage B.H1(t+2), A.H0(t+2) | Q(4,2) | vmcnt(6)
    stageH(BgH1 + kS2, lBb + 8192);
    stageH(Ag + kS2, lAb);
    PH_MFMA(4, 2);
    VMCNT(6);
    __builtin_amdgcn_s_barrier();

    // ---- ph5: rd af[0-3]+bf[0-1] of t+1 | stage A.H1(t+2) | lgkm(8) | Q(0,0)
    RD_A(0, lA1); RD_B(0, lB1);
    stageH(Ag + (size_t)128 * K + kS2, lAb + 8192);
    asm volatile("s_waitcnt lgkmcnt(8)" ::: "memory");
    PH_MFMA(0, 0);
    __builtin_amdgcn_s_barrier();

    // ---- ph6: rd bf[2-3] of t+1 | Q(0,2)
    RD_B(2, lB1);
    PH_MFMA(0, 2);
    __builtin_amdgcn_s_barrier();

    // ---- ph7: rd af[4-7] of t+1 | stage B.H0(t+3) | Q(4,0)
    RD_A(4, lA1);
    stageH(BgH0 + kS3, lBb + 16384);
    PH_MFMA(4, 0);
    __builtin_amdgcn_s_barrier();

    // ---- ph8: stage B.H1(t+3), A.H0(t+3) | Q(4,2) | vmcnt(6)
    stageH(BgH1 + kS3, lBb + 16384 + 8192);
    stageH(Ag + kS3, lAb + 16384);
    PH_MFMA(4, 2);
    VMCNT(6);
    __builtin_amdgcn_s_barrier();
  }
  VMCNT(0);  // drain tail stages (all waves' LDS writes) before exit/reuse

#undef RD_A
#undef RD_B
#undef PH_MFMA

  if constexpr (EPI == 3) {
    // ---------- fused epilogue: cross-wave combine via LDS (128KiB now free) ----------
    __builtin_amdgcn_s_barrier();  // all waves' tail stages landed before LDS reuse
    // exchange region r (r=0..3): sh + r*16384 shorts = 8192 floats each.
    if (wc >= 2) {
      // up-wave: dump acc f32, lane-contiguous (conflict-free)
      float* rg = (float*)(sh + (wr * 2 + (wc - 2)) * 16384);
#pragma unroll
      for (int m = 0; m < 8; ++m)
#pragma unroll
        for (int n = 0; n < 4; ++n)
#pragma unroll
          for (int j = 0; j < 4; ++j)
            rg[(m * 16 + n * 4 + j) * 64 + lane] = acc[m][n][j];
    }
    asm volatile("s_waitcnt lgkmcnt(0)" ::: "memory");
    __builtin_amdgcn_s_barrier();
    if (wc < 2) {
      // gate-wave: read matching up values (same lane/frag map), combine, store h
      const float* rg = (const float*)(sh + (wr * 2 + wc) * 16384);
      const int row0 = brow * 256 + wr * 128 + lk * 4;
      const int col0 = bcol * 128 + wc * 64 + lr;
#pragma unroll
      for (int m = 0; m < 8; ++m)
#pragma unroll
        for (int n = 0; n < 4; ++n)
#pragma unroll
          for (int j = 0; j < 4; ++j) {
            float g = acc[m][n][j];
            float u = rg[(m * 16 + n * 4 + j) * 64 + lane];
            float s = g / (1.0f + __expf(-g));  // silu
            ((unsigned short*)Cout)[(size_t)(row0 + m * 16 + j) * N + (col0 + n * 16)] =
                f2bf_rne(s * u);
          }
    }
  } else {
    // Epilogue. C/D frag layout (measured, m89/m91): col = lane&15, row = (lane>>4)*4 + j
    const int row0 = brow * 256 + wr * 128 + lk * 4;
    const int col0 = bcol * 256 + wc * 64 + lr;
#pragma unroll
    for (int m = 0; m < 8; ++m)
#pragma unroll
      for (int n = 0; n < 4; ++n)
#pragma unroll
        for (int j = 0; j < 4; ++j) {
          size_t idx = (size_t)(row0 + m * 16 + j) * N + (col0 + n * 16);
          ((float*)Cout)[idx] = acc[m][n][j];
        }
  }
}

extern "C" void kernel_launch(void* const* d_in, const int* in_sizes, int n_in,
                              void* d_out, int out_size, void* d_ws, size_t ws_size,
                              hipStream_t stream) {
  const float* x  = (const float*)d_in[0];
  const float* w1 = (const float*)d_in[1];
  const float* w2 = (const float*)d_in[2];
  const float* w3 = (const float*)d_in[3];
  float* out = (float*)d_out;

  const int M = M_ROWS, E = E_DIM, H = H_DIM;

  // ws layout (bf16 elements):
  //   [0, 32MB)   xb   (reused for w3b after fused gate+up GEMM)
  //   [32, 64MB)  w1b
  //   [64, 96MB)  w2b
  //   [96, 224MB) h (written directly by fused kernel; gate never materialized)
  unsigned short* xb  = (unsigned short*)d_ws;
  unsigned short* w1b = xb + (size_t)M * E;
  unsigned short* w2b = w1b + (size_t)H * E;
  unsigned short* hb  = w2b + (size_t)H * E;
  unsigned short* w3b = xb;  // safe: cvt(w3) is stream-ordered after fused GEMM reads xb

  const int n8 = (M * E) / 8;  // == (H*E)/8 == (E*H)/8 == 2097152
  // convert x, w1, w2 in one launch (3 segments)
  cvt3_f32_bf16<<<dim3(n8 / 256, 3), 256, 0, stream>>>(x, xb, w1, w1b, w2, w2b, n8);

  // h = silu(x w1^T) * (x w2^T) -> bf16 [M, H]  (fused split-N dual GEMM)
  gemm256<3><<<dim3(H / 128, M / 256), 512, 0, stream>>>(xb, w1b, w2b, hb, M, H, E);

  cvt3_f32_bf16<<<dim3(n8 / 256, 1), 256, 0, stream>>>(w3, w3b, w3, w3b, w3, w3b, n8);

  // out = h w3^T -> fp32 [M, E]
  gemm256<0><<<dim3(E / 256, M / 256), 512, 0, stream>>>(hb, w3b, nullptr, out, M, E, H);
}

// Round 12
// 803.124 us; speedup vs baseline: 1.2928x; 1.0365x over previous
//
#include <hip/hip_runtime.h>
#include <hip/hip_bf16.h>

// Problem dims (fixed by reference): x[B*S=8192, E=2048], w1/w2[H=8192, E], w3[E, H]
#define M_ROWS 8192
#define E_DIM  2048
#define H_DIM  8192

typedef __attribute__((ext_vector_type(8))) short bf16x8;
typedef __attribute__((ext_vector_type(4))) float f32x4;
typedef __attribute__((ext_vector_type(4))) unsigned int uint4v;

__device__ __forceinline__ unsigned short f2bf_rne(float x) {
  unsigned u = __builtin_bit_cast(unsigned, x);
  u += 0x7FFFu + ((u >> 16) & 1u);
  return (unsigned short)(u >> 16);
}

// ---------------- fp32 -> bf16 conversion, 3 segments per launch ----------------
__global__ __launch_bounds__(256) void cvt3_f32_bf16(const float* __restrict__ s0, unsigned short* __restrict__ d0,
                                                     const float* __restrict__ s1, unsigned short* __restrict__ d1,
                                                     const float* __restrict__ s2, unsigned short* __restrict__ d2,
                                                     int n8) {
  int i = blockIdx.x * blockDim.x + threadIdx.x;
  if (i >= n8) return;
  const float* in = (blockIdx.y == 0) ? s0 : (blockIdx.y == 1) ? s1 : s2;
  unsigned short* out = (blockIdx.y == 0) ? d0 : (blockIdx.y == 1) ? d1 : d2;
  const float4* p = (const float4*)(in + (size_t)i * 8);
  float4 a = p[0];
  float4 b = p[1];
  union { unsigned short us[8]; uint4v v; } r;
  r.us[0] = f2bf_rne(a.x); r.us[1] = f2bf_rne(a.y);
  r.us[2] = f2bf_rne(a.z); r.us[3] = f2bf_rne(a.w);
  r.us[4] = f2bf_rne(b.x); r.us[5] = f2bf_rne(b.y);
  r.us[6] = f2bf_rne(b.z); r.us[7] = f2bf_rne(b.w);
  *(uint4v*)(out + (size_t)i * 8) = r.v;
}

// ---------------- async global -> LDS, 16B per lane ----------------
__device__ __forceinline__ void gld_lds16(const unsigned short* g, unsigned short* l) {
  __builtin_amdgcn_global_load_lds(
      (const __attribute__((address_space(1))) unsigned int*)g,
      (__attribute__((address_space(3))) unsigned int*)l, 16, 0, 0);
}

#define VMCNT(n)   asm volatile("s_waitcnt vmcnt(" #n ")" ::: "memory")

// =============== 256-row 8-phase/2-K-tile GEMM (m201 cadence, R7/R10-verified) ===============
// 512 threads (8 waves 2Mx4N), BK=64, buf0=even buf1=odd K-tiles, 128KiB LDS (single
// flat array: lA = sh, lB = sh+32768), XOR-swizzled LDS reads via pre-swizzled global
// source (linear LDS dest), setprio on MFMA, vmcnt(6) at ph4/ph8 (loads aged 3-5
// phases), lgkm(8) hint on 12-read phases. Phase skeleton + stage cadence IDENTICAL
// to R10 (verified passing, fused 621us). Only change vs R10: block-index mapping.
// EPI=0: single-B 256x256 tile, fp32 store (down-proj). XCD swizzle (row-sharing).
// EPI=3: FUSED gate+up (256 rows x 128 cols of BOTH matmuls). XCD COLUMN-CHUNKING:
//   xcd=wg&7 owns bcols [8*xcd, 8*xcd+8) and sweeps brow -> concurrent working set
//   4 x-panels + 8 weight panels (12MB) instead of 33MB streamed; cuts L2-miss/HBM
//   refetch (measured 1.13GB for 96MB unique).
template <int EPI>
__global__ __launch_bounds__(512, 2)
void gemm256(const unsigned short* __restrict__ A,
             const unsigned short* __restrict__ B,
             const unsigned short* __restrict__ B2,
             void* __restrict__ Cout,
             int M, int N, int K) {
  __shared__ unsigned short sh[65536];     // 128KiB: [0,32768)=lA dbuf, [32768,65536)=lB dbuf
  unsigned short* lAb = sh;                // lA[parity] = lAb + parity*16384
  unsigned short* lBb = sh + 32768;        // lB[parity] = lBb + parity*16384

  const int tid = threadIdx.x;
  const int lane = tid & 63;
  const int wave = tid >> 6;
  const int wr = wave >> 2;   // 0..1  (128 output rows each)
  const int wc = wave & 3;    // 0..3
  const int lr = lane & 15, lk = lane >> 4;

  const int gx = gridDim.x;
  const int wg = blockIdx.y * gx + blockIdx.x;
  int bcol, brow;
  if constexpr (EPI == 3) {
    // XCD column-chunking (bijective: wg = (brow*8 + (bcol&7))*8 + (bcol>>3))
    const int xcd = wg & 7, idx = wg >> 3;
    bcol = xcd * 8 + (idx & 7);
    brow = idx >> 3;
  } else {
    // bijective XCD swizzle (nwg % 8 == 0)
    const int nwg = gx * gridDim.y;
    const int swz = (wg & 7) * (nwg >> 3) + (wg >> 3);
    bcol = swz % gx;
    brow = swz / gx;
  }

  const unsigned short* Ag = A + (size_t)brow * 256 * K;
  const unsigned short* BgH0;  // source for B-LDS rows 0-127
  const unsigned short* BgH1;  // source for B-LDS rows 128-255
  if constexpr (EPI == 3) {
    BgH0 = B  + (size_t)bcol * 128 * K;   // w1 panel
    BgH1 = B2 + (size_t)bcol * 128 * K;   // w2 panel
  } else {
    BgH0 = B + (size_t)bcol * 256 * K;
    BgH1 = BgH0 + (size_t)128 * K;
  }

  f32x4 acc[8][4] = {};
  const int NT = K >> 6;
  const int NI = NT >> 1;

  // stage one 128x64 half-tile: linear LDS dest (lane*16B), inverse-swizzled global src
  auto stageH = [&](const unsigned short* gbase, unsigned short* ldsh) {
#pragma unroll
    for (int i = 0; i < 2; ++i) {
      int p = i * 4096 + tid * 8;               // physical element offset in half
      int row = p >> 6;                          // 0..127
      int lslot = ((p >> 3) & 7) ^ (row & 7);    // logical 8-elem slot
      gld_lds16(gbase + (size_t)row * K + lslot * 8, ldsh + p);
    }
  };

  const int xsw = (lr & 7) << 3;  // read-side swizzle XOR (element units)
  bf16x8 af[8][2], bf[4][2];

#define RD_A(MLO, SRC) \
  _Pragma("unroll") for (int m = MLO; m < MLO + 4; ++m) { \
    int r = wr * 128 + m * 16 + lr; \
    af[m][0] = *(const bf16x8*)&SRC[(r * 64 + lk * 8) ^ xsw]; \
    af[m][1] = *(const bf16x8*)&SRC[(r * 64 + 32 + lk * 8) ^ xsw]; }
#define RD_B(NLO, SRC) \
  _Pragma("unroll") for (int n = NLO; n < NLO + 2; ++n) { \
    int r = wc * 64 + n * 16 + lr; \
    bf[n][0] = *(const bf16x8*)&SRC[(r * 64 + lk * 8) ^ xsw]; \
    bf[n][1] = *(const bf16x8*)&SRC[(r * 64 + 32 + lk * 8) ^ xsw]; }
#define PH_MFMA(MLO, NLO) \
  __builtin_amdgcn_s_barrier(); \
  asm volatile("s_waitcnt lgkmcnt(0)" ::: "memory"); \
  __builtin_amdgcn_sched_barrier(0); \
  __builtin_amdgcn_s_setprio(1); \
  _Pragma("unroll") for (int m = MLO; m < MLO + 4; ++m) \
  _Pragma("unroll") for (int n = NLO; n < NLO + 2; ++n) \
  _Pragma("unroll") for (int ks = 0; ks < 2; ++ks) \
    acc[m][n] = __builtin_amdgcn_mfma_f32_16x16x32_bf16(af[m][ks], bf[n][ks], acc[m][n], 0, 0, 0); \
  __builtin_amdgcn_s_setprio(0);

  // ---------------- prologue: stage tiles 0 and 1 fully; drain; barrier ----------------
  stageH(Ag, lAb);
  stageH(Ag + (size_t)128 * K, lAb + 8192);
  stageH(BgH0, lBb);
  stageH(BgH1, lBb + 8192);
  stageH(Ag + 64, lAb + 16384);
  stageH(Ag + (size_t)128 * K + 64, lAb + 16384 + 8192);
  stageH(BgH0 + 64, lBb + 16384);
  stageH(BgH1 + 64, lBb + 16384 + 8192);
  VMCNT(0);
  __builtin_amdgcn_s_barrier();

  const unsigned short* lA0 = lAb;
  const unsigned short* lB0 = lBb;
  const unsigned short* lA1 = lAb + 16384;
  const unsigned short* lB1 = lBb + 16384;

  for (int it = 0; it < NI; ++it) {
    const int t = it << 1;
    const size_t kT1 = (size_t)(t + 1) * 64;
    const size_t kS2 = (size_t)((t + 2 < NT) ? t + 2 : NT - 1) * 64;
    const size_t kS3 = (size_t)((t + 3 < NT) ? t + 3 : NT - 1) * 64;

    // ---- ph1: rd af[0-3]+bf[0-1] (12) | stage A.H1(t+1) | lgkm(8) | Q(0,0)
    RD_A(0, lA0); RD_B(0, lB0);
    if (it > 0) stageH(Ag + (size_t)128 * K + kT1, lAb + 16384 + 8192);
    asm volatile("s_waitcnt lgkmcnt(8)" ::: "memory");
    PH_MFMA(0, 0);
    __builtin_amdgcn_s_barrier();

    // ---- ph2: rd bf[2-3] (4) | Q(0,2)
    RD_B(2, lB0);
    PH_MFMA(0, 2);
    __builtin_amdgcn_s_barrier();

    // ---- ph3: rd af[4-7] (8) | stage B.H0(t+2) | Q(4,0)
    RD_A(4, lA0);
    stageH(BgH0 + kS2, lBb);
    PH_MFMA(4, 0);
    __builtin_amdgcn_s_barrier();

    // ---- ph4: stage B.H1(t+2), A.H0(t+2) | Q(4,2) | vmcnt(6)
    stageH(BgH1 + kS2, lBb + 8192);
    stageH(Ag + kS2, lAb);
    PH_MFMA(4, 2);
    VMCNT(6);
    __builtin_amdgcn_s_barrier();

    // ---- ph5: rd af[0-3]+bf[0-1] of t+1 | stage A.H1(t+2) | lgkm(8) | Q(0,0)
    RD_A(0, lA1); RD_B(0, lB1);
    stageH(Ag + (size_t)128 * K + kS2, lAb + 8192);
    asm volatile("s_waitcnt lgkmcnt(8)" ::: "memory");
    PH_MFMA(0, 0);
    __builtin_amdgcn_s_barrier();

    // ---- ph6: rd bf[2-3] of t+1 | Q(0,2)
    RD_B(2, lB1);
    PH_MFMA(0, 2);
    __builtin_amdgcn_s_barrier();

    // ---- ph7: rd af[4-7] of t+1 | stage B.H0(t+3) | Q(4,0)
    RD_A(4, lA1);
    stageH(BgH0 + kS3, lBb + 16384);
    PH_MFMA(4, 0);
    __builtin_amdgcn_s_barrier();

    // ---- ph8: stage B.H1(t+3), A.H0(t+3) | Q(4,2) | vmcnt(6)
    stageH(BgH1 + kS3, lBb + 16384 + 8192);
    stageH(Ag + kS3, lAb + 16384);
    PH_MFMA(4, 2);
    VMCNT(6);
    __builtin_amdgcn_s_barrier();
  }
  VMCNT(0);  // drain tail stages (all waves' LDS writes) before exit/reuse

#undef RD_A
#undef RD_B
#undef PH_MFMA

  if constexpr (EPI == 3) {
    // ---------- fused epilogue: cross-wave combine via LDS (128KiB now free) ----------
    __builtin_amdgcn_s_barrier();  // all waves' tail stages landed before LDS reuse
    // exchange region r (r=0..3): sh + r*16384 shorts = 8192 floats each.
    if (wc >= 2) {
      // up-wave: dump acc f32, lane-contiguous (conflict-free)
      float* rg = (float*)(sh + (wr * 2 + (wc - 2)) * 16384);
#pragma unroll
      for (int m = 0; m < 8; ++m)
#pragma unroll
        for (int n = 0; n < 4; ++n)
#pragma unroll
          for (int j = 0; j < 4; ++j)
            rg[(m * 16 + n * 4 + j) * 64 + lane] = acc[m][n][j];
    }
    asm volatile("s_waitcnt lgkmcnt(0)" ::: "memory");
    __builtin_amdgcn_s_barrier();
    if (wc < 2) {
      // gate-wave: read matching up values (same lane/frag map), combine, store h
      const float* rg = (const float*)(sh + (wr * 2 + wc) * 16384);
      const int row0 = brow * 256 + wr * 128 + lk * 4;
      const int col0 = bcol * 128 + wc * 64 + lr;
#pragma unroll
      for (int m = 0; m < 8; ++m)
#pragma unroll
        for (int n = 0; n < 4; ++n)
#pragma unroll
          for (int j = 0; j < 4; ++j) {
            float g = acc[m][n][j];
            float u = rg[(m * 16 + n * 4 + j) * 64 + lane];
            float s = g / (1.0f + __expf(-g));  // silu
            ((unsigned short*)Cout)[(size_t)(row0 + m * 16 + j) * N + (col0 + n * 16)] =
                f2bf_rne(s * u);
          }
    }
  } else {
    // Epilogue. C/D frag layout (measured, m89/m91): col = lane&15, row = (lane>>4)*4 + j
    const int row0 = brow * 256 + wr * 128 + lk * 4;
    const int col0 = bcol * 256 + wc * 64 + lr;
#pragma unroll
    for (int m = 0; m < 8; ++m)
#pragma unroll
      for (int n = 0; n < 4; ++n)
#pragma unroll
        for (int j = 0; j < 4; ++j) {
          size_t idx = (size_t)(row0 + m * 16 + j) * N + (col0 + n * 16);
          ((float*)Cout)[idx] = acc[m][n][j];
        }
  }
}

extern "C" void kernel_launch(void* const* d_in, const int* in_sizes, int n_in,
                              void* d_out, int out_size, void* d_ws, size_t ws_size,
                              hipStream_t stream) {
  const float* x  = (const float*)d_in[0];
  const float* w1 = (const float*)d_in[1];
  const float* w2 = (const float*)d_in[2];
  const float* w3 = (const float*)d_in[3];
  float* out = (float*)d_out;

  const int M = M_ROWS, E = E_DIM, H = H_DIM;

  // ws layout (bf16 elements):
  //   [0, 32MB)   xb   (reused for w3b after fused gate+up GEMM)
  //   [32, 64MB)  w1b
  //   [64, 96MB)  w2b
  //   [96, 224MB) h (written directly by fused kernel; gate never materialized)
  unsigned short* xb  = (unsigned short*)d_ws;
  unsigned short* w1b = xb + (size_t)M * E;
  unsigned short* w2b = w1b + (size_t)H * E;
  unsigned short* hb  = w2b + (size_t)H * E;
  unsigned short* w3b = xb;  // safe: cvt(w3) is stream-ordered after fused GEMM reads xb

  const int n8 = (M * E) / 8;  // == (H*E)/8 == (E*H)/8 == 2097152
  // convert x, w1, w2 in one launch (3 segments)
  cvt3_f32_bf16<<<dim3(n8 / 256, 3), 256, 0, stream>>>(x, xb, w1, w1b, w2, w2b, n8);

  // h = silu(x w1^T) * (x w2^T) -> bf16 [M, H]  (fused split-N dual GEMM)
  gemm256<3><<<dim3(H / 128, M / 256), 512, 0, stream>>>(xb, w1b, w2b, hb, M, H, E);

  cvt3_f32_bf16<<<dim3(n8 / 256, 1), 256, 0, stream>>>(w3, w3b, w3, w3b, w3, w3b, n8);

  // out = h w3^T -> fp32 [M, E]
  gemm256<0><<<dim3(E / 256, M / 256), 512, 0, stream>>>(hb, w3b, nullptr, out, M, E, H);
}